// Round 1
// 2508.762 us; speedup vs baseline: 1.0171x; 1.0171x over previous
//
#include <hip/hip_runtime.h>

// Problem constants (SIZE=68, SSN=8 -> C=9, S1=69, BATCH=256)
#define C9     9
#define S1     69
#define JT     621            // C9*S1: one (class,pos) plane
#define NBATCH 256
#define NSTEP  68
#define QJ     4761           // 69*69   (Q j-stride, P s-major plane size)
#define QI     42849          // 9*69*69 (Q i-stride; also P batch stride)
#define BROW   42849          // 69 planes * 621 per-batch alpha
#define ALPHA_N (NBATCH*BROW)
#define QTFL   385664         // padded float count of QT region in ws
#define LI     72             // LDS la row stride (16B aligned)
#define NEGINF (-__builtin_inff())

// ---------------------------------------------------------------------------
// qtrans: QT[c][t][i][s] = Q[c][i][s][t]  (per-(c,i) 69x69 LDS plane transpose)
// Used only by the backtrace phase for coalesced Q reads (mode >= 1).
__global__ void qtrans_kernel(const float* __restrict__ Q, float* __restrict__ QT)
{
  __shared__ float tile[69*70];
  const int pl = blockIdx.x;           // c*9 + i
  const int c = pl / 9, i = pl - c*9;
  const float* src = Q + (size_t)pl*QJ;
  for (int f = threadIdx.x; f < QJ; f += 256){
    const int s = f / S1, t = f - s*S1;
    tile[s*70 + t] = src[f];
  }
  __syncthreads();
  float* dst = QT + (size_t)c*QI + i*S1;     // + t*621 + s
  for (int f = threadIdx.x; f < QJ; f += 256){
    const int t = f / S1, s = f - t*S1;
    dst[t*JT + s] = tile[s*70 + t];
  }
}

// ---------------------------------------------------------------------------
// mega: one block per PAIR of batches; everything (prep, 68 max-plus steps,
// per-step m/logsumexp reductions, n/D prefix, addc, backtrace) fused so the
// scan runs with only __syncthreads() between steps: Q/P stay L2-resident,
// la stays in LDS, no atomics, no inter-kernel cache flushes.
__global__ __launch_bounds__(640) void mega_kernel(
    const float* __restrict__ P, const float* __restrict__ Q,
    const float* __restrict__ pi, const float* __restrict__ Tp,
    const int* __restrict__ ls, float* __restrict__ out,
    const float* __restrict__ QT, int mode)
{
  __shared__ __align__(16) float la[2][2][C9*LI];  // [batch][buf][i*LI+s]
  __shared__ float m_sh[2][NSTEP+1];
  __shared__ float lse_sh[2][NSTEP+1];
  __shared__ float n_sh[2][NSTEP+1];
  __shared__ float red[2][10];
  __shared__ float sred[2][10];
  __shared__ float sbest[2][10];
  __shared__ int   sidx[2][10];
  __shared__ int   sct[4];

  const int tid  = threadIdx.x;
  const int w    = tid >> 6;
  const int lane = tid & 63;
  const int b0   = blockIdx.x * 2;
  const int b1   = b0 + 1;
  const bool valid = tid < JT;
  const int e  = valid ? tid : (JT-1);
  const int j  = e / S1;
  const int t  = e - j*S1;
  const float Tv = Tp[0];

  float* out0 = out + (size_t)b0*BROW;
  float* out1 = out + (size_t)b1*BROW;

  // ---- prep: v[0] raw (pi at s==0, else -inf); m[0], lse_v[0] ----
  {
    const float v0 = (t == 0) ? pi[j] : NEGINF;
    if (valid){
      out0[68*JT + e] = v0;
      out1[68*JT + e] = v0;
      la[0][0][j*LI + t] = v0;
      la[1][0][j*LI + t] = v0;
    }
    if (tid == 0){
      float mx = pi[0];
      #pragma unroll
      for (int c = 1; c < C9; ++c) mx = fmaxf(mx, pi[c]);
      float sm = 0.f;
      #pragma unroll
      for (int c = 0; c < C9; ++c) sm += expf(pi[c] - mx);
      const float l0 = mx + logf(sm);
      m_sh[0][0] = mx;  m_sh[1][0] = mx;
      lse_sh[0][0] = l0; lse_sh[1][0] = l0;
    }
  }
  __syncthreads();

  float mprev0 = m_sh[0][0];
  float mprev1 = m_sh[1][0];

  const float* qp  = Q + j*QJ + t;                         // + i*QI + s*S1
  const float* pp0 = P + (size_t)(b0*C9 + j)*QJ + t;       // + s*S1
  const float* pp1 = pp0 + QI;                             // batch stride == QI

  // ---- 68 max-plus steps ----
  int cur = 0;
  for (int k = 1; k <= NSTEP; ++k){
    const float* laA = la[0][cur];
    const float* laB = la[1][cur];
    float acc0 = NEGINF, acc1 = NEGINF;

    #pragma unroll 2
    for (int u = 0; u < 17; ++u){                          // s = 4u .. 4u+3
      const int so = 4*u*S1;
      float r0x=NEGINF, r0y=NEGINF, r0z=NEGINF, r0w=NEGINF;
      float r1x=NEGINF, r1y=NEGINF, r1z=NEGINF, r1w=NEGINF;
      #pragma unroll
      for (int i = 0; i < C9; ++i){
        const float* q = qp + i*QI + so;
        const float qx = q[0], qy = q[S1], qz = q[2*S1], qw = q[3*S1];
        const float4 lA = *(const float4*)(laA + i*LI + 4*u);
        const float4 lB = *(const float4*)(laB + i*LI + 4*u);
        r0x = fmaxf(r0x, fmaf(Tv, qx, lA.x));
        r0y = fmaxf(r0y, fmaf(Tv, qy, lA.y));
        r0z = fmaxf(r0z, fmaf(Tv, qz, lA.z));
        r0w = fmaxf(r0w, fmaf(Tv, qw, lA.w));
        r1x = fmaxf(r1x, fmaf(Tv, qx, lB.x));
        r1y = fmaxf(r1y, fmaf(Tv, qy, lB.y));
        r1z = fmaxf(r1z, fmaf(Tv, qz, lB.z));
        r1w = fmaxf(r1w, fmaf(Tv, qw, lB.w));
      }
      const float pa0 = pp0[so], pa1 = pp0[so+S1], pa2 = pp0[so+2*S1], pa3 = pp0[so+3*S1];
      acc0 = fmaxf(acc0, fmaxf(fmaxf(pa0+r0x, pa1+r0y), fmaxf(pa2+r0z, pa3+r0w)));
      const float pb0 = pp1[so], pb1 = pp1[so+S1], pb2 = pp1[so+2*S1], pb3 = pp1[so+3*S1];
      acc1 = fmaxf(acc1, fmaxf(fmaxf(pb0+r1x, pb1+r1y), fmaxf(pb2+r1z, pb3+r1w)));
    }
    { // tail s = 68 (keeps all Q/P reads in-bounds)
      const int so = 68*S1;
      float rA = NEGINF, rB = NEGINF;
      #pragma unroll
      for (int i = 0; i < C9; ++i){
        const float q = qp[i*QI + so];
        rA = fmaxf(rA, fmaf(Tv, q, laA[i*LI + 68]));
        rB = fmaxf(rB, fmaf(Tv, q, laB[i*LI + 68]));
      }
      acc0 = fmaxf(acc0, pp0[so] + rA);
      acc1 = fmaxf(acc1, pp1[so] + rB);
    }

    const float v0 = acc0 - mprev0;
    const float v1 = acc1 - mprev1;
    if (valid){
      out0[(68-k)*JT + e] = v0;
      out1[(68-k)*JT + e] = v1;
      la[0][cur^1][j*LI + t] = v0;
      la[1][cur^1][j*LI + t] = v1;
    }

    // block max -> m[k]
    float w0 = valid ? v0 : NEGINF;
    float w1 = valid ? v1 : NEGINF;
    #pragma unroll
    for (int o = 32; o >= 1; o >>= 1){
      w0 = fmaxf(w0, __shfl_down(w0, o));
      w1 = fmaxf(w1, __shfl_down(w1, o));
    }
    if (lane == 0){ red[0][w] = w0; red[1][w] = w1; }
    __syncthreads();                                       // (A)
    float mA = red[0][0], mB = red[1][0];
    #pragma unroll
    for (int q = 1; q < 10; ++q){
      mA = fmaxf(mA, red[0][q]);
      mB = fmaxf(mB, red[1][q]);
    }

    // block sum of exp(v - m) -> lse_v[k]
    float s0 = valid ? expf(v0 - mA) : 0.f;
    float s1 = valid ? expf(v1 - mB) : 0.f;
    #pragma unroll
    for (int o = 32; o >= 1; o >>= 1){
      s0 += __shfl_down(s0, o);
      s1 += __shfl_down(s1, o);
    }
    if (lane == 0){ sred[0][w] = s0; sred[1][w] = s1; }
    __syncthreads();                                       // (B)
    if (tid == 0){
      float sA = sred[0][0], sB = sred[1][0];
      #pragma unroll
      for (int q = 1; q < 10; ++q){ sA += sred[0][q]; sB += sred[1][q]; }
      m_sh[0][k] = mA;  m_sh[1][k] = mB;
      lse_sh[0][k] = mA + logf(sA);
      lse_sh[1][k] = mB + logf(sB);
    }
    mprev0 = mA; mprev1 = mB;
    cur ^= 1;
  }
  __syncthreads();

  // ---- n[k] = lse_v[k] + D[k], D[k] = sum_{kk<k} m[kk] (double) ----
  if (tid == 0){
    double d0 = 0.0, d1 = 0.0;
    for (int k = 0; k <= NSTEP; ++k){
      n_sh[0][k] = (float)((double)lse_sh[0][k] + d0);
      n_sh[1][k] = (float)((double)lse_sh[1][k] + d1);
      d0 += (double)m_sh[0][k];
      d1 += (double)m_sh[1][k];
    }
  }
  __syncthreads();

  // ---- addc: alpha[b][K] = v[68-K] + (n[K] - lse_v[68-K]), clamp -3e38 ----
  // Each thread RMWs only the elements it wrote itself.
  if (valid){
    for (int K = 0; K < NSTEP+1; ++K){
      const float C0 = n_sh[0][K] - lse_sh[0][68-K];
      const float C1 = n_sh[1][K] - lse_sh[1][68-K];
      float* r0 = out0 + (size_t)K*JT + e;
      float* r1 = out1 + (size_t)K*JT + e;
      *r0 = fmaxf(*r0 + C0, -3.0e38f);
      *r1 = fmaxf(*r1 + C1, -3.0e38f);
    }
  }
  __syncthreads();

  // ---- backtrace: both batches' serial chains interleaved for ILP ----
  {
    int c0 = 3, tt0 = ls[b0];
    int c1 = 3, tt1 = ls[b1];
    float* mpb0 = out + (size_t)ALPHA_N + (size_t)b0*(69*3);
    float* mpb1 = out + (size_t)ALPHA_N + (size_t)b1*(69*3);
    if (tid == 0){
      mpb0[68*3+0] = 3.f; mpb0[68*3+1] = 0.f; mpb0[68*3+2] = (float)tt0;
      mpb0[67*3+1] = 0.f;
      mpb1[68*3+0] = 3.f; mpb1[68*3+1] = 0.f; mpb1[68*3+2] = (float)tt1;
      mpb1[67*3+1] = 0.f;
    }
    const int m9 = j;    // candidate previous state index (e/69)
    const int sm = t;    // candidate s (e%69)

    float av0 = valid ? out0[1*JT + e] : NEGINF;
    float av1 = valid ? out1[1*JT + e] : NEGINF;

    for (int r = 1; r <= NSTEP; ++r){
      float avn0 = NEGINF, avn1 = NEGINF;
      if (r < NSTEP && valid){
        avn0 = out0[(size_t)(r+1)*JT + e];
        avn1 = out1[(size_t)(r+1)*JT + e];
      }
      float best0 = NEGINF, best1 = NEGINF;
      int   bi0 = 0x7fffffff, bi1 = 0x7fffffff;
      if (valid){
        float q0, q1;
        if (mode >= 1){
          q0 = QT[(size_t)(c0*S1 + tt0)*JT + e];
          q1 = QT[(size_t)(c1*S1 + tt1)*JT + e];
        } else {
          q0 = Q[c0*QI + m9*QJ + sm*S1 + tt0];
          q1 = Q[c1*QI + m9*QJ + sm*S1 + tt1];
        }
        const float p0v = P[(size_t)(b0*C9 + c0)*QJ + sm*S1 + tt0];
        const float p1v = P[(size_t)(b1*C9 + c1)*QJ + sm*S1 + tt1];
        best0 = (p0v + Tv*q0) + av0; bi0 = e;   // exact ref association
        best1 = (p1v + Tv*q1) + av1; bi1 = e;
      }
      // argmax: strict > with min-index tie-break == jnp.argmax first-occurrence
      #pragma unroll
      for (int o = 32; o >= 1; o >>= 1){
        const float ov0 = __shfl_down(best0, o); const int oi0 = __shfl_down(bi0, o);
        if (ov0 > best0 || (ov0 == best0 && oi0 < bi0)){ best0 = ov0; bi0 = oi0; }
        const float ov1 = __shfl_down(best1, o); const int oi1 = __shfl_down(bi1, o);
        if (ov1 > best1 || (ov1 == best1 && oi1 < bi1)){ best1 = ov1; bi1 = oi1; }
      }
      if (lane == 0){
        sbest[0][w] = best0; sidx[0][w] = bi0;
        sbest[1][w] = best1; sidx[1][w] = bi1;
      }
      __syncthreads();
      if (tid == 0){
        float bb = sbest[0][0]; int bi = sidx[0][0];
        #pragma unroll
        for (int q = 1; q < 10; ++q)
          if (sbest[0][q] > bb || (sbest[0][q] == bb && sidx[0][q] < bi)){
            bb = sbest[0][q]; bi = sidx[0][q];
          }
        int cn = bi / S1, tn = bi - (bi/S1)*S1;
        mpb0[(68-r)*3 + 0] = (float)cn;
        mpb0[(68-r)*3 + 2] = (float)tn;
        if (r <= 67) mpb0[(67-r)*3 + 1] = (float)(tn - tt0);
        sct[0] = cn; sct[1] = tn;

        bb = sbest[1][0]; bi = sidx[1][0];
        #pragma unroll
        for (int q = 1; q < 10; ++q)
          if (sbest[1][q] > bb || (sbest[1][q] == bb && sidx[1][q] < bi)){
            bb = sbest[1][q]; bi = sidx[1][q];
          }
        cn = bi / S1; tn = bi - (bi/S1)*S1;
        mpb1[(68-r)*3 + 0] = (float)cn;
        mpb1[(68-r)*3 + 2] = (float)tn;
        if (r <= 67) mpb1[(67-r)*3 + 1] = (float)(tn - tt1);
        sct[2] = cn; sct[3] = tn;
      }
      __syncthreads();
      c0 = sct[0]; tt0 = sct[1];
      c1 = sct[2]; tt1 = sct[3];
      av0 = avn0; av1 = avn1;
    }
  }
}

// ---------------------------------------------------------------------------
extern "C" void kernel_launch(void* const* d_in, const int* in_sizes, int n_in,
                              void* d_out, int out_size, void* d_ws, size_t ws_size,
                              hipStream_t stream)
{
  const float* P  = (const float*)d_in[0];
  const float* Q  = (const float*)d_in[1];
  const float* pi = (const float*)d_in[2];
  const float* T  = (const float*)d_in[3];
  const int*   ls = (const int*)d_in[4];

  float* out = (float*)d_out;

  // ws-based transposed Q for coalesced backtrace reads (launch-invariant
  // branch -> graph-safe).
  int mode = 0; float* QT = nullptr;
  if (ws_size >= (size_t)QTFL*4){ mode = 1; QT = (float*)d_ws; }

  if (mode >= 1) qtrans_kernel<<<81, 256, 0, stream>>>(Q, QT);
  mega_kernel<<<NBATCH/2, 640, 0, stream>>>(P, Q, pi, T, ls, out, QT, mode);
}

// Round 2
// 1993.111 us; speedup vs baseline: 1.2802x; 1.2587x over previous
//
#include <hip/hip_runtime.h>

// Problem constants (SIZE=68, SSN=8 -> C=9, S1=69, BATCH=256)
#define C9     9
#define S1     69
#define JT     621            // C9*S1: one (class,pos) plane
#define NBATCH 256
#define NSTEP  68
#define QJ     4761           // 69*69   (Q j-stride, P s-major plane size)
#define QI     42849          // 9*69*69 (Q i-stride; also P batch stride)
#define BROW   42849          // 69 planes * 621 per-batch alpha
#define ALPHA_N (NBATCH*BROW)
#define QTFL   385664         // padded float count of QT region in ws
#define NEGINF (-__builtin_inff())

// float4 with 4-byte alignment guarantee: Q/P rows have odd stride 69, so
// 16B-aligned vector loads are impossible; gfx950 global loads support
// dword-aligned dwordx4, and this typedef tells clang the true alignment.
typedef float float4u __attribute__((ext_vector_type(4), aligned(4)));

// ---------------------------------------------------------------------------
// qtrans: QT[c][t][i][s] = Q[c][i][s][t]  (per-(c,i) 69x69 LDS plane transpose)
// Used only by the backtrace phase for coalesced Q reads (mode >= 1).
__global__ void qtrans_kernel(const float* __restrict__ Q, float* __restrict__ QT)
{
  __shared__ float tile[69*70];
  const int pl = blockIdx.x;           // c*9 + i
  const int c = pl / 9, i = pl - c*9;
  const float* src = Q + (size_t)pl*QJ;
  for (int f = threadIdx.x; f < QJ; f += 256){
    const int s = f / S1, t = f - s*S1;
    tile[s*70 + t] = src[f];
  }
  __syncthreads();
  float* dst = QT + (size_t)c*QI + i*S1;     // + t*621 + s
  for (int f = threadIdx.x; f < QJ; f += 256){
    const int t = f / S1, s = f - t*S1;
    dst[t*JT + s] = tile[s*70 + t];
  }
}

// ---------------------------------------------------------------------------
// mega v2: ONE batch per block, grid 256 (all CUs).  704 threads = 11 waves:
// 4 s-groups x 162 (j,t-quad) slots.  Each thread computes 4 outputs
// (t = t0..t0+3) as float4 Q/P loads (t is innermost dim of both tensors),
// partial over its s-range; groups combine via LDS (fmax is exact, so the
// regrouping is bit-identical to the verified kernel).  Q stays L2-resident
// per XCD (1.5 MB < 4 MB, shared by all 32 blocks on the XCD).
#define SLO(g) ((g)==0 ? 0 : (g)==1 ? 18 : (g)==2 ? 35 : 52)
#define SHI(g) ((g)==0 ? 18 : (g)==1 ? 35 : (g)==2 ? 52 : 69)

#define LOADS(QB, PB, SS) { \
  const float* qs_ = qb + (SS)*S1; \
  _Pragma("unroll") \
  for (int i_ = 0; i_ < C9; ++i_) QB[i_] = *(const float4u*)(qs_ + i_*QI); \
  PB = *(const float4u*)(pb + (SS)*S1); }

#define COMPS(QB, PB, SS) { \
  float r0=NEGINF, r1=NEGINF, r2=NEGINF, r3=NEGINF; \
  _Pragma("unroll") \
  for (int i_ = 0; i_ < C9; ++i_){ \
    const float lv_ = laC[i_*72 + (SS)]; \
    r0 = fmaxf(r0, fmaf(Tv, QB[i_].x, lv_)); \
    r1 = fmaxf(r1, fmaf(Tv, QB[i_].y, lv_)); \
    r2 = fmaxf(r2, fmaf(Tv, QB[i_].z, lv_)); \
    r3 = fmaxf(r3, fmaf(Tv, QB[i_].w, lv_)); \
  } \
  a0 = fmaxf(a0, PB.x + r0); a1 = fmaxf(a1, PB.y + r1); \
  a2 = fmaxf(a2, PB.z + r2); a3 = fmaxf(a3, PB.w + r3); }

__global__ __launch_bounds__(704) void mega_kernel(
    const float* __restrict__ P, const float* __restrict__ Q,
    const float* __restrict__ pi, const float* __restrict__ Tp,
    const int* __restrict__ ls, float* __restrict__ out,
    const float* __restrict__ QT, int mode)
{
  __shared__ __align__(16) float la[2][C9*72];   // la[buf][i*72 + s]
  __shared__ float part[4][162][4];              // per-group partial maxes
  __shared__ float red[11], sred[11];
  __shared__ float m_sh[NSTEP+1], lse_sh[NSTEP+1], n_sh[NSTEP+1];
  __shared__ float sbest[11];
  __shared__ int   sidx[11];
  __shared__ int   sct[2];

  const int tid  = threadIdx.x;
  const int w    = tid >> 6;
  const int b    = blockIdx.x;
  const bool act = tid < 648;
  const int gg   = act ? tid / 162 : 3;          // s-group 0..3
  const int slot = act ? tid - (tid/162)*162 : 0;
  const int j    = slot / 18;                    // output class 0..8
  const int tq   = slot - j*18;                  // t-quad 0..17
  const int t0   = (tq < 17) ? 4*tq : 65;        // tq=17 covers t=65..68; only t=68 owned
  const int s_lo = SLO(gg), s_hi = SHI(gg);
  const float Tv = Tp[0];

  float* outb = out + (size_t)b*BROW;

  // ---- prep: v[0] raw (pi at s==0, else -inf); m[0], lse_v[0] ----
  for (int e = tid; e < JT; e += 704){
    const int i = e / S1, s = e - i*S1;
    const float v0 = (s == 0) ? pi[i] : NEGINF;
    outb[68*JT + e] = v0;
    la[0][i*72 + s] = v0;
  }
  if (tid == 0){
    float mx = pi[0];
    #pragma unroll
    for (int c = 1; c < C9; ++c) mx = fmaxf(mx, pi[c]);
    float sm = 0.f;
    #pragma unroll
    for (int c = 0; c < C9; ++c) sm += expf(pi[c] - mx);
    m_sh[0]   = mx;
    lse_sh[0] = mx + logf(sm);
  }
  __syncthreads();
  float mprev = m_sh[0];

  const float* qb = Q + j*QJ + t0;                       // + i*QI + s*S1
  const float* pb = P + (size_t)(b*C9 + j)*QJ + t0;      // + s*S1

  // ---- 68 max-plus steps ----
  int cur = 0;
  for (int k = 1; k <= NSTEP; ++k){
    const float* laC = la[cur];
    float a0 = NEGINF, a1 = NEGINF, a2 = NEGINF, a3 = NEGINF;
    if (act){
      float4u qA[C9], qB[C9], pA, pB;
      int s = s_lo;
      LOADS(qA, pA, s)
      for (; s + 2 < s_hi; s += 2){
        LOADS(qB, pB, s+1)
        COMPS(qA, pA, s)
        LOADS(qA, pA, s+2)
        COMPS(qB, pB, s+1)
      }
      if (s + 1 < s_hi){
        LOADS(qB, pB, s+1)
        COMPS(qA, pA, s)
        COMPS(qB, pB, s+1)
      } else {
        COMPS(qA, pA, s)
      }
      if (gg > 0){
        part[gg][slot][0] = a0; part[gg][slot][1] = a1;
        part[gg][slot][2] = a2; part[gg][slot][3] = a3;
      }
    }
    __syncthreads();                                     // (A) partials ready

    float mval = NEGINF;
    if (act && gg == 0){
      const float v0 = fmaxf(fmaxf(a0, part[1][slot][0]),
                             fmaxf(part[2][slot][0], part[3][slot][0])) - mprev;
      const float v1 = fmaxf(fmaxf(a1, part[1][slot][1]),
                             fmaxf(part[2][slot][1], part[3][slot][1])) - mprev;
      const float v2 = fmaxf(fmaxf(a2, part[1][slot][2]),
                             fmaxf(part[2][slot][2], part[3][slot][2])) - mprev;
      const float v3 = fmaxf(fmaxf(a3, part[1][slot][3]),
                             fmaxf(part[2][slot][3], part[3][slot][3])) - mprev;
      float* dst = outb + (size_t)(68-k)*JT + j*S1 + t0;
      if (tq < 17){
        float4u vv; vv.x = v0; vv.y = v1; vv.z = v2; vv.w = v3;
        *(float4u*)dst = vv;
        *(float4*)(&la[cur^1][j*72 + t0]) = make_float4(v0, v1, v2, v3);
        mval = fmaxf(fmaxf(v0, v1), fmaxf(v2, v3));
      } else {                                           // owns only t=68
        dst[3] = v3;
        la[cur^1][j*72 + 68] = v3;
        mval = v3;
      }
      // stash v for the lse pass (registers survive the barrier)
      a0 = v0; a1 = v1; a2 = v2; a3 = v3;
    }

    // block max -> m[k]  (only g0 waves 0..2 hold real values)
    float mr = mval;
    #pragma unroll
    for (int o = 32; o >= 1; o >>= 1) mr = fmaxf(mr, __shfl_down(mr, o));
    if ((tid & 63) == 0) red[w] = mr;
    __syncthreads();                                     // (B)
    float mA = red[0];
    mA = fmaxf(mA, red[1]);
    mA = fmaxf(mA, red[2]);

    // block sum of exp(v - m) -> lse_v[k]
    float sv = 0.f;
    if (act && gg == 0){
      if (tq < 17) sv = expf(a0 - mA) + expf(a1 - mA) + expf(a2 - mA) + expf(a3 - mA);
      else         sv = expf(a3 - mA);
    }
    #pragma unroll
    for (int o = 32; o >= 1; o >>= 1) sv += __shfl_down(sv, o);
    if ((tid & 63) == 0) sred[w] = sv;
    __syncthreads();                                     // (C)
    if (tid == 0){
      const float S = sred[0] + sred[1] + sred[2];
      m_sh[k]   = mA;
      lse_sh[k] = mA + logf(S);
    }
    mprev = mA;
    cur ^= 1;
  }
  __syncthreads();

  // ---- n[k] = lse_v[k] + D[k], D[k] = sum_{kk<k} m[kk] (double) ----
  if (tid == 0){
    double d = 0.0;
    for (int kk = 0; kk <= NSTEP; ++kk){
      n_sh[kk] = (float)((double)lse_sh[kk] + d);
      d += (double)m_sh[kk];
    }
  }
  __syncthreads();

  // ---- addc: alpha[K] = v[68-K] + (n[K] - lse_v[68-K]), clamp -3e38 ----
  for (int K = 0; K <= NSTEP; ++K){
    const float Cst = n_sh[K] - lse_sh[68-K];
    for (int e = tid; e < JT; e += 704){
      float* r = outb + (size_t)K*JT + e;
      *r = fmaxf(*r + Cst, -3.0e38f);
    }
  }
  __syncthreads();

  // ---- backtrace: 621 candidates, one per thread ----
  {
    int c = 3, t2 = ls[b];
    float* mpb = out + (size_t)ALPHA_N + (size_t)b*(69*3);
    if (tid == 0){
      mpb[68*3+0] = 3.f; mpb[68*3+1] = 0.f; mpb[68*3+2] = (float)t2;
      mpb[67*3+1] = 0.f;   // l_0 = 0 after the shift
    }
    const bool vok = tid < JT;
    const int etid = vok ? tid : 0;
    const int im = etid / S1;
    const int sm = etid - im*S1;
    float av = vok ? outb[1*JT + tid] : NEGINF;
    for (int r = 1; r <= NSTEP; ++r){
      float avn = NEGINF;
      if (r < NSTEP && vok) avn = outb[(size_t)(r+1)*JT + tid];
      float best = NEGINF; int bidx = 0x7fffffff;
      if (vok){
        float qv;
        if (mode >= 1) qv = QT[(size_t)(c*S1 + t2)*JT + tid];
        else           qv = Q[c*QI + im*QJ + sm*S1 + t2];
        const float pv = P[(size_t)(b*C9 + c)*QJ + sm*S1 + t2];
        best = (pv + Tv*qv) + av;   // exact ref association
        bidx = tid;
      }
      // argmax: strict > with min-index tie-break == jnp.argmax first-occurrence
      #pragma unroll
      for (int o = 32; o >= 1; o >>= 1){
        const float ov = __shfl_down(best, o); const int oi = __shfl_down(bidx, o);
        if (ov > best || (ov == best && oi < bidx)){ best = ov; bidx = oi; }
      }
      if ((tid & 63) == 0){ sbest[w] = best; sidx[w] = bidx; }
      __syncthreads();
      if (tid == 0){
        float bb = sbest[0]; int bi = sidx[0];
        #pragma unroll
        for (int q = 1; q < 11; ++q)
          if (sbest[q] > bb || (sbest[q] == bb && sidx[q] < bi)){
            bb = sbest[q]; bi = sidx[q];
          }
        const int cn = bi / S1, tn = bi - cn*S1;
        mpb[(68-r)*3 + 0] = (float)cn;
        mpb[(68-r)*3 + 2] = (float)tn;
        if (r <= 67) mpb[(67-r)*3 + 1] = (float)(tn - t2);
        sct[0] = cn; sct[1] = tn;
      }
      __syncthreads();
      c = sct[0]; t2 = sct[1];
      av = avn;
    }
  }
}

// ---------------------------------------------------------------------------
extern "C" void kernel_launch(void* const* d_in, const int* in_sizes, int n_in,
                              void* d_out, int out_size, void* d_ws, size_t ws_size,
                              hipStream_t stream)
{
  const float* P  = (const float*)d_in[0];
  const float* Q  = (const float*)d_in[1];
  const float* pi = (const float*)d_in[2];
  const float* T  = (const float*)d_in[3];
  const int*   ls = (const int*)d_in[4];

  float* out = (float*)d_out;

  // ws-based transposed Q for coalesced backtrace reads (launch-invariant
  // branch -> graph-safe).
  int mode = 0; float* QT = nullptr;
  if (ws_size >= (size_t)QTFL*4){ mode = 1; QT = (float*)d_ws; }

  if (mode >= 1) qtrans_kernel<<<81, 256, 0, stream>>>(Q, QT);
  mega_kernel<<<NBATCH, 704, 0, stream>>>(P, Q, pi, T, ls, out, QT, mode);
}